// Round 2
// baseline (180.287 us; speedup 1.0000x reference)
//
#include <hip/hip_runtime.h>
#include <cstdint>
#include <cstddef>

// Problem constants: W is [COUT, CIN]; x is [4*4096, CIN]. All I/O fp32.
#define CIN  1024
#define COUT 1024

// ---------- fp32 -> bf16 (round-to-nearest-even) ----------
__device__ __forceinline__ unsigned short f2bf(float f) {
    union { float f; unsigned int i; } v;
    v.f = f;
    unsigned int u = v.i;
    u += 0x7FFFu + ((u >> 16) & 1u);
    return (unsigned short)(u >> 16);
}

// ---------- kernel 1: zero the fp32 W accumulation buffer (1M floats) ----------
__global__ void zero_f32(float4* __restrict__ p) {
    p[blockIdx.x * 256 + threadIdx.x] = float4{0.f, 0.f, 0.f, 0.f};
}

// ---------- kernel 2: scatter-add fp32 COO values into dense fp32 W ----------
__global__ void scatter_add(const float* __restrict__ vals,
                            const int* __restrict__ rows,
                            const int* __restrict__ cols,
                            float* __restrict__ W, int nnz) {
    int i = blockIdx.x * 256 + threadIdx.x;
    if (i < nnz) {
        atomicAdd(W + (size_t)rows[i] * CIN + cols[i], vals[i]);
    }
}

// ---------- kernel 3: fp32 W -> bf16 W ----------
__global__ void cvt_bf16(const float* __restrict__ src, unsigned short* __restrict__ dst) {
    int i = (blockIdx.x * 256 + threadIdx.x) * 4;
    float4 v = *(const float4*)(src + i);
    ushort4 o;
    o.x = f2bf(v.x); o.y = f2bf(v.y); o.z = f2bf(v.z); o.w = f2bf(v.w);
    *(ushort4*)(dst + i) = o;
}

// ---------- kernel 4: GEMM C[M,N] = A[M,K](fp32) * B[N,K](bf16)^T -> fp32 ----------
// m97-style 128x128x64 tile, 4 waves (2x2), 4x4 mfma_f32_16x16x32_bf16 per wave.
// B staged with global_load_lds width=16; A staged fp32->bf16 via cvt + ds_write_b128.
typedef __attribute__((ext_vector_type(8))) short bf16x8;
typedef __attribute__((ext_vector_type(4))) float f32x4;

__global__ __launch_bounds__(256) void gemm_af32_bbf16(
    const float* __restrict__ A,            // [M, K] fp32
    const unsigned short* __restrict__ B,   // [N, K] bf16 (W layout = B^T)
    float* __restrict__ C,                  // [M, N] fp32
    int M) {
    constexpr int K = CIN;
    constexpr int N = COUT;

    __shared__ __align__(16) unsigned short As[128 * 64];
    __shared__ __align__(16) unsigned short Bs[128 * 64];

    const int tid   = threadIdx.x;
    const int lane  = tid & 63;
    const int wave  = tid >> 6;
    const int waveM = (wave >> 1) * 64;   // 2x2 wave grid over 128x128 tile
    const int waveN = (wave & 1) * 64;
    const int quad  = lane >> 4;
    const int l16   = lane & 15;

    const int rowA0 = blockIdx.x * 128;   // M-tile origin
    const int rowB0 = blockIdx.y * 128;   // N-tile origin

    // Staging map: thread t handles row m = it*32 + (t>>3), k = (t&7)*8 .. +8.
    // LDS elem offset = it*2048 + t*8 (row-major [128][64], contiguous per wave:
    // global_load_lds needs wave-uniform base + lane*16B — t*16B satisfies it).
    const int stg_m = tid >> 3;           // 0..31
    const int stg_k = (tid & 7) * 8;      // 0,8,...,56
    const float*          pa = A + (size_t)(rowA0 + stg_m) * K + stg_k;
    const unsigned short* pb = B + (size_t)(rowB0 + stg_m) * K + stg_k;
    const int ldsoff = tid * 8;           // elements

    f32x4 acc[4][4] = {};

    for (int k0 = 0; k0 < K; k0 += 64) {
        // B: async global->LDS (bf16, 16B per lane) — issue first, overlaps A work.
#pragma unroll
        for (int it = 0; it < 4; ++it) {
            __builtin_amdgcn_global_load_lds(
                (const __attribute__((address_space(1))) void*)(pb + k0 + (size_t)it * 32 * K),
                (__attribute__((address_space(3))) void*)(Bs + it * 2048 + ldsoff),
                16, 0, 0);
        }
        // A: fp32 loads -> bf16 cvt -> LDS. Each 8-lane group writes 128
        // contiguous LDS bytes -> conflict-free ds_write_b128.
#pragma unroll
        for (int it = 0; it < 4; ++it) {
            const float* s = pa + k0 + (size_t)it * 32 * K;
            float4 v0 = *(const float4*)(s);
            float4 v1 = *(const float4*)(s + 4);
            union { bf16x8 v; unsigned short u[8]; } w;
            w.u[0] = f2bf(v0.x); w.u[1] = f2bf(v0.y);
            w.u[2] = f2bf(v0.z); w.u[3] = f2bf(v0.w);
            w.u[4] = f2bf(v1.x); w.u[5] = f2bf(v1.y);
            w.u[6] = f2bf(v1.z); w.u[7] = f2bf(v1.w);
            *(bf16x8*)(As + it * 2048 + ldsoff) = w.v;
        }
        __syncthreads();  // drains vmcnt (global_load_lds) + lgkmcnt (ds_write)

#pragma unroll
        for (int ks = 0; ks < 2; ++ks) {
            bf16x8 af[4], bfr[4];
#pragma unroll
            for (int t = 0; t < 4; ++t) {
                // A-operand layout: A[m = lane&15][k = quad*8 + j]
                af[t]  = *(const bf16x8*)(As + (waveM + t * 16 + l16) * 64 + ks * 32 + quad * 8);
                // B-operand (B^T source): lane holds B[k = quad*8+j][n = lane&15]
                bfr[t] = *(const bf16x8*)(Bs + (waveN + t * 16 + l16) * 64 + ks * 32 + quad * 8);
            }
#pragma unroll
            for (int i = 0; i < 4; ++i)
#pragma unroll
                for (int j = 0; j < 4; ++j)
                    acc[i][j] = __builtin_amdgcn_mfma_f32_16x16x32_bf16(
                        af[i], bfr[j], acc[i][j], 0, 0, 0);
        }
        __syncthreads();
    }

    // Epilogue: C/D layout col = lane&15, row = quad*4 + r (m89-verified). fp32 out.
#pragma unroll
    for (int i = 0; i < 4; ++i) {
#pragma unroll
        for (int r = 0; r < 4; ++r) {
            const int row = rowA0 + waveM + i * 16 + quad * 4 + r;
            float* cp = C + (size_t)row * N + rowB0 + waveN + l16;
#pragma unroll
            for (int j = 0; j < 4; ++j)
                cp[j * 16] = acc[i][j][r];
        }
    }
}

extern "C" void kernel_launch(void* const* d_in, const int* in_sizes, int n_in,
                              void* d_out, int out_size, void* d_ws, size_t ws_size,
                              hipStream_t stream) {
    const float* x    = (const float*)d_in[0];   // [M, CIN] fp32
    const float* vals = (const float*)d_in[1];   // [nnz] fp32
    const int*   idx  = (const int*)d_in[2];     // [2, nnz] int32

    float* out = (float*)d_out;                  // [M, COUT] fp32

    const int nnz = in_sizes[2] / 2;
    const int M   = in_sizes[0] / CIN;

    float*          Wf = (float*)d_ws;                                                        // 4 MB
    unsigned short* Wb = (unsigned short*)((char*)d_ws + (size_t)COUT * CIN * sizeof(float)); // 2 MB

    // 1) zero fp32 W (ws is poisoned 0xAA before every call)
    zero_f32<<<dim3(COUT * CIN / (256 * 4)), dim3(256), 0, stream>>>((float4*)Wf);
    // 2) scatter-add duplicates like coalesce()
    scatter_add<<<dim3((nnz + 255) / 256), dim3(256), 0, stream>>>(vals, idx, idx + nnz, Wf, nnz);
    // 3) W -> bf16 for MFMA
    cvt_bf16<<<dim3(COUT * CIN / (256 * 4)), dim3(256), 0, stream>>>(Wf, Wb);
    // 4) GEMM: out = x @ W^T
    gemm_af32_bbf16<<<dim3(M / 128, COUT / 128), dim3(256), 0, stream>>>(x, Wb, out, M);
}

// Round 3
// 174.253 us; speedup vs baseline: 1.0346x; 1.0346x over previous
//
#include <hip/hip_runtime.h>
#include <cstdint>
#include <cstddef>

// Problem constants: W is [COUT, CIN]; x is [4*4096, CIN]. All I/O fp32.
#define CIN  1024
#define COUT 1024

typedef __attribute__((ext_vector_type(8))) short bf16x8;
typedef __attribute__((ext_vector_type(4))) float f32x4;

// ---------- fp32 -> bf16 (round-to-nearest-even) ----------
__device__ __forceinline__ unsigned short f2bf(float f) {
    union { float f; unsigned int i; } v;
    v.f = f;
    unsigned int u = v.i;
    u += 0x7FFFu + ((u >> 16) & 1u);
    return (unsigned short)(u >> 16);
}

// ---------- kernel 1: zero the fp32 W accumulation buffer (1M floats) ----------
__global__ void zero_f32(float4* __restrict__ p) {
    p[blockIdx.x * 256 + threadIdx.x] = float4{0.f, 0.f, 0.f, 0.f};
}

// ---------- kernel 2: scatter-add fp32 COO values into dense fp32 W ----------
__global__ void scatter_add(const float* __restrict__ vals,
                            const int* __restrict__ rows,
                            const int* __restrict__ cols,
                            float* __restrict__ W, int nnz) {
    int i = blockIdx.x * 256 + threadIdx.x;
    if (i < nnz) {
        atomicAdd(W + (size_t)rows[i] * CIN + cols[i], vals[i]);
    }
}

// ---------- kernel 3: fp32 -> bf16 bulk convert (used for W and for x) ----------
__global__ void cvt_bf16_bulk(const float* __restrict__ src, unsigned short* __restrict__ dst) {
    size_t i = ((size_t)blockIdx.x * 256 + threadIdx.x) * 8;
    float4 v0 = *(const float4*)(src + i);
    float4 v1 = *(const float4*)(src + i + 4);
    union { bf16x8 v; unsigned short u[8]; } w;
    w.u[0] = f2bf(v0.x); w.u[1] = f2bf(v0.y); w.u[2] = f2bf(v0.z); w.u[3] = f2bf(v0.w);
    w.u[4] = f2bf(v1.x); w.u[5] = f2bf(v1.y); w.u[6] = f2bf(v1.z); w.u[7] = f2bf(v1.w);
    *(bf16x8*)(dst + i) = w.v;
}

// ---------- kernel 4a: m97-structure GEMM, A bf16 + B bf16, fp32 out ----------
// C[M,N] = A[M,K] * B[N,K]^T. 128x128x64 tile, 4 waves (2x2), 4x4
// mfma_f32_16x16x32_bf16 per wave. Both operands staged via
// global_load_lds width=16 (wave-uniform base + lane*16).
__global__ __launch_bounds__(256) void gemm_bt_bf16(
    const unsigned short* __restrict__ A,   // [M, K] bf16
    const unsigned short* __restrict__ B,   // [N, K] bf16
    float* __restrict__ C,                  // [M, N] fp32
    int M) {
    constexpr int K = CIN;
    constexpr int N = COUT;

    __shared__ __align__(16) unsigned short As[128 * 64];
    __shared__ __align__(16) unsigned short Bs[128 * 64];

    const int tid   = threadIdx.x;
    const int lane  = tid & 63;
    const int wave  = tid >> 6;
    const int waveM = (wave >> 1) * 64;
    const int waveN = (wave & 1) * 64;
    const int quad  = lane >> 4;
    const int l16   = lane & 15;

    const int rowA0 = blockIdx.x * 128;
    const int rowB0 = blockIdx.y * 128;

    const int stg_m = tid >> 3;           // 0..31
    const int stg_k = (tid & 7) * 8;      // 0,8,...,56
    const unsigned short* pa = A + (size_t)(rowA0 + stg_m) * K + stg_k;
    const unsigned short* pb = B + (size_t)(rowB0 + stg_m) * K + stg_k;
    const int ldsoff = tid * 8;

    f32x4 acc[4][4] = {};

    for (int k0 = 0; k0 < K; k0 += 64) {
#pragma unroll
        for (int it = 0; it < 4; ++it) {
            __builtin_amdgcn_global_load_lds(
                (const __attribute__((address_space(1))) void*)(pa + k0 + (size_t)it * 32 * K),
                (__attribute__((address_space(3))) void*)(As + it * 2048 + ldsoff),
                16, 0, 0);
            __builtin_amdgcn_global_load_lds(
                (const __attribute__((address_space(1))) void*)(pb + k0 + (size_t)it * 32 * K),
                (__attribute__((address_space(3))) void*)(Bs + it * 2048 + ldsoff),
                16, 0, 0);
        }
        __syncthreads();

#pragma unroll
        for (int ks = 0; ks < 2; ++ks) {
            bf16x8 af[4], bfr[4];
#pragma unroll
            for (int t = 0; t < 4; ++t) {
                af[t]  = *(const bf16x8*)(As + (waveM + t * 16 + l16) * 64 + ks * 32 + quad * 8);
                bfr[t] = *(const bf16x8*)(Bs + (waveN + t * 16 + l16) * 64 + ks * 32 + quad * 8);
            }
#pragma unroll
            for (int i = 0; i < 4; ++i)
#pragma unroll
                for (int j = 0; j < 4; ++j)
                    acc[i][j] = __builtin_amdgcn_mfma_f32_16x16x32_bf16(
                        af[i], bfr[j], acc[i][j], 0, 0, 0);
        }
        __syncthreads();
    }

#pragma unroll
    for (int i = 0; i < 4; ++i) {
#pragma unroll
        for (int r = 0; r < 4; ++r) {
            const int row = rowA0 + waveM + i * 16 + quad * 4 + r;
            float* cp = C + (size_t)row * N + rowB0 + waveN + l16;
#pragma unroll
            for (int j = 0; j < 4; ++j)
                cp[j * 16] = acc[i][j][r];
        }
    }
}

// ---------- kernel 4b: fallback GEMM (A fp32 cvt in-kernel) — round-2 kernel ----------
__global__ __launch_bounds__(256) void gemm_af32_bbf16(
    const float* __restrict__ A,
    const unsigned short* __restrict__ B,
    float* __restrict__ C,
    int M) {
    constexpr int K = CIN;
    constexpr int N = COUT;

    __shared__ __align__(16) unsigned short As[128 * 64];
    __shared__ __align__(16) unsigned short Bs[128 * 64];

    const int tid   = threadIdx.x;
    const int lane  = tid & 63;
    const int wave  = tid >> 6;
    const int waveM = (wave >> 1) * 64;
    const int waveN = (wave & 1) * 64;
    const int quad  = lane >> 4;
    const int l16   = lane & 15;

    const int rowA0 = blockIdx.x * 128;
    const int rowB0 = blockIdx.y * 128;

    const int stg_m = tid >> 3;
    const int stg_k = (tid & 7) * 8;
    const float*          pa = A + (size_t)(rowA0 + stg_m) * K + stg_k;
    const unsigned short* pb = B + (size_t)(rowB0 + stg_m) * K + stg_k;
    const int ldsoff = tid * 8;

    f32x4 acc[4][4] = {};

    for (int k0 = 0; k0 < K; k0 += 64) {
#pragma unroll
        for (int it = 0; it < 4; ++it) {
            __builtin_amdgcn_global_load_lds(
                (const __attribute__((address_space(1))) void*)(pb + k0 + (size_t)it * 32 * K),
                (__attribute__((address_space(3))) void*)(Bs + it * 2048 + ldsoff),
                16, 0, 0);
        }
#pragma unroll
        for (int it = 0; it < 4; ++it) {
            const float* s = pa + k0 + (size_t)it * 32 * K;
            float4 v0 = *(const float4*)(s);
            float4 v1 = *(const float4*)(s + 4);
            union { bf16x8 v; unsigned short u[8]; } w;
            w.u[0] = f2bf(v0.x); w.u[1] = f2bf(v0.y);
            w.u[2] = f2bf(v0.z); w.u[3] = f2bf(v0.w);
            w.u[4] = f2bf(v1.x); w.u[5] = f2bf(v1.y);
            w.u[6] = f2bf(v1.z); w.u[7] = f2bf(v1.w);
            *(bf16x8*)(As + it * 2048 + ldsoff) = w.v;
        }
        __syncthreads();

#pragma unroll
        for (int ks = 0; ks < 2; ++ks) {
            bf16x8 af[4], bfr[4];
#pragma unroll
            for (int t = 0; t < 4; ++t) {
                af[t]  = *(const bf16x8*)(As + (waveM + t * 16 + l16) * 64 + ks * 32 + quad * 8);
                bfr[t] = *(const bf16x8*)(Bs + (waveN + t * 16 + l16) * 64 + ks * 32 + quad * 8);
            }
#pragma unroll
            for (int i = 0; i < 4; ++i)
#pragma unroll
                for (int j = 0; j < 4; ++j)
                    acc[i][j] = __builtin_amdgcn_mfma_f32_16x16x32_bf16(
                        af[i], bfr[j], acc[i][j], 0, 0, 0);
        }
        __syncthreads();
    }

#pragma unroll
    for (int i = 0; i < 4; ++i) {
#pragma unroll
        for (int r = 0; r < 4; ++r) {
            const int row = rowA0 + waveM + i * 16 + quad * 4 + r;
            float* cp = C + (size_t)row * N + rowB0 + waveN + l16;
#pragma unroll
            for (int j = 0; j < 4; ++j)
                cp[j * 16] = acc[i][j][r];
        }
    }
}

extern "C" void kernel_launch(void* const* d_in, const int* in_sizes, int n_in,
                              void* d_out, int out_size, void* d_ws, size_t ws_size,
                              hipStream_t stream) {
    const float* x    = (const float*)d_in[0];   // [M, CIN] fp32
    const float* vals = (const float*)d_in[1];   // [nnz] fp32
    const int*   idx  = (const int*)d_in[2];     // [2, nnz] int32

    float* out = (float*)d_out;                  // [M, COUT] fp32

    const int nnz = in_sizes[2] / 2;
    const int M   = in_sizes[0] / CIN;

    const size_t wf_bytes = (size_t)COUT * CIN * sizeof(float);          // 4 MB
    const size_t wb_bytes = (size_t)COUT * CIN * sizeof(unsigned short); // 2 MB
    const size_t xb_bytes = (size_t)M * CIN * sizeof(unsigned short);    // 32 MB

    float*          Wf = (float*)d_ws;
    unsigned short* Wb = (unsigned short*)((char*)d_ws + wf_bytes);
    unsigned short* Xb = (unsigned short*)((char*)d_ws + wf_bytes + wb_bytes);

    // 1) zero fp32 W (ws is poisoned 0xAA before every call)
    zero_f32<<<dim3(COUT * CIN / (256 * 4)), dim3(256), 0, stream>>>((float4*)Wf);
    // 2) scatter-add duplicates like coalesce()
    scatter_add<<<dim3((nnz + 255) / 256), dim3(256), 0, stream>>>(vals, idx, idx + nnz, Wf, nnz);
    // 3) W -> bf16
    cvt_bf16_bulk<<<dim3(COUT * CIN / (256 * 8)), dim3(256), 0, stream>>>(Wf, Wb);

    if (ws_size >= wf_bytes + wb_bytes + xb_bytes) {
        // 4) x -> bf16 (pure streaming, ~96 MB of HBM traffic)
        cvt_bf16_bulk<<<dim3((unsigned)((size_t)M * CIN / (256 * 8))), dim3(256), 0, stream>>>(x, Xb);
        // 5) m97-structure GEMM: both operands via global_load_lds
        gemm_bt_bf16<<<dim3(M / 128, COUT / 128), dim3(256), 0, stream>>>(Xb, Wb, out, M);
    } else {
        // Fallback: in-kernel A conversion (round-2 path)
        gemm_af32_bbf16<<<dim3(M / 128, COUT / 128), dim3(256), 0, stream>>>(x, Wb, out, M);
    }
}

// Round 4
// 163.840 us; speedup vs baseline: 1.1004x; 1.0636x over previous
//
#include <hip/hip_runtime.h>
#include <cstdint>
#include <cstddef>

// Problem constants: W is [COUT, CIN]; x is [4*4096, CIN]. All I/O fp32.
#define CIN  1024
#define COUT 1024

typedef __attribute__((ext_vector_type(8))) short bf16x8;
typedef __attribute__((ext_vector_type(4))) float f32x4;

// ---------- fp32 -> bf16 (round-to-nearest-even) ----------
__device__ __forceinline__ unsigned short f2bf(float f) {
    union { float f; unsigned int i; } v;
    v.f = f;
    unsigned int u = v.i;
    u += 0x7FFFu + ((u >> 16) & 1u);
    return (unsigned short)(u >> 16);
}

// ---------- kernel 1: zero the fp32 W accumulation buffer (1M floats) ----------
__global__ void zero_f32(float4* __restrict__ p) {
    p[blockIdx.x * 256 + threadIdx.x] = float4{0.f, 0.f, 0.f, 0.f};
}

// ---------- kernel 2: scatter-add fp32 COO values into dense fp32 W ----------
__global__ void scatter_add(const float* __restrict__ vals,
                            const int* __restrict__ rows,
                            const int* __restrict__ cols,
                            float* __restrict__ W, int nnz) {
    int i = blockIdx.x * 256 + threadIdx.x;
    if (i < nnz) {
        atomicAdd(W + (size_t)rows[i] * CIN + cols[i], vals[i]);
    }
}

// ---------- kernel 3: fp32 -> bf16 bulk convert (used for W and for x) ----------
__global__ void cvt_bf16_bulk(const float* __restrict__ src, unsigned short* __restrict__ dst) {
    size_t i = ((size_t)blockIdx.x * 256 + threadIdx.x) * 8;
    float4 v0 = *(const float4*)(src + i);
    float4 v1 = *(const float4*)(src + i + 4);
    union { bf16x8 v; unsigned short u[8]; } w;
    w.u[0] = f2bf(v0.x); w.u[1] = f2bf(v0.y); w.u[2] = f2bf(v0.z); w.u[3] = f2bf(v0.w);
    w.u[4] = f2bf(v1.x); w.u[5] = f2bf(v1.y); w.u[6] = f2bf(v1.z); w.u[7] = f2bf(v1.w);
    *(bf16x8*)(dst + i) = w.v;
}

// ---------- kernel 4: m97-structure GEMM with XOR-swizzled LDS ----------
// C[M,N] = A[M,K](bf16) * B[N,K](bf16)^T -> fp32. 128x128x64 tile, 4 waves
// (2x2), 4x4 mfma_f32_16x16x32_bf16 per wave.
//
// LDS layout (per operand, [128 rows][8 chunks of 16B]): chunk slot for
// (row r, data-chunk c) is  slot = c ^ (r & 7).
//   - Staging: global_load_lds forces LDS dst = wave-base + lane*16B, so the
//     swizzle is applied on the GLOBAL source side: the lane owning slot
//     (r, c_slot) fetches data-chunk c_slot ^ (r&7). Permutation stays inside
//     the row's 128 B segment -> global coalescing unchanged.
//   - Fragment reads: chunk index (ks*4+quad) ^ (l16&7) -> the 16-lane group
//     spreads across all 8 bank-quads (2-way aliasing only, free per m136),
//     instead of the unswizzled 128B-stride ~16-way conflict.
__global__ __launch_bounds__(256) void gemm_bt_bf16_sw(
    const unsigned short* __restrict__ A,   // [M, K] bf16
    const unsigned short* __restrict__ B,   // [N, K] bf16
    float* __restrict__ C,                  // [M, N] fp32
    int M) {
    constexpr int K = CIN;
    constexpr int N = COUT;

    __shared__ __align__(16) unsigned short As[128 * 64];
    __shared__ __align__(16) unsigned short Bs[128 * 64];

    const int tid   = threadIdx.x;
    const int lane  = tid & 63;
    const int wave  = tid >> 6;
    const int waveM = (wave >> 1) * 64;
    const int waveN = (wave & 1) * 64;
    const int quad  = lane >> 4;
    const int l16   = lane & 15;

    const int rowA0 = blockIdx.x * 128;
    const int rowB0 = blockIdx.y * 128;

    // Staging map with source-side swizzle.
    const int stg_r  = tid >> 3;                 // 0..31 (row within 32-row group)
    const int c_slot = tid & 7;                  // LDS 16B-chunk slot in row
    const int c_data = c_slot ^ (stg_r & 7);     // global chunk to fetch
    const unsigned short* pa = A + (size_t)(rowA0 + stg_r) * K + c_data * 8;
    const unsigned short* pb = B + (size_t)(rowB0 + stg_r) * K + c_data * 8;
    const int ldsoff = tid * 8;                  // elements (= lane*16B + wave base)

    f32x4 acc[4][4] = {};

    for (int k0 = 0; k0 < K; k0 += 64) {
#pragma unroll
        for (int it = 0; it < 4; ++it) {
            __builtin_amdgcn_global_load_lds(
                (const __attribute__((address_space(1))) void*)(pa + k0 + (size_t)it * 32 * K),
                (__attribute__((address_space(3))) void*)(As + it * 2048 + ldsoff),
                16, 0, 0);
            __builtin_amdgcn_global_load_lds(
                (const __attribute__((address_space(1))) void*)(pb + k0 + (size_t)it * 32 * K),
                (__attribute__((address_space(3))) void*)(Bs + it * 2048 + ldsoff),
                16, 0, 0);
        }
        __syncthreads();

        const int s7 = l16 & 7;
#pragma unroll
        for (int ks = 0; ks < 2; ++ks) {
            bf16x8 af[4], bfr[4];
            const int cx = ((ks * 4 + quad) ^ s7) * 8;   // swizzled k-chunk offset
#pragma unroll
            for (int t = 0; t < 4; ++t) {
                af[t]  = *(const bf16x8*)(As + (waveM + t * 16 + l16) * 64 + cx);
                bfr[t] = *(const bf16x8*)(Bs + (waveN + t * 16 + l16) * 64 + cx);
            }
#pragma unroll
            for (int i = 0; i < 4; ++i)
#pragma unroll
                for (int j = 0; j < 4; ++j)
                    acc[i][j] = __builtin_amdgcn_mfma_f32_16x16x32_bf16(
                        af[i], bfr[j], acc[i][j], 0, 0, 0);
        }
        __syncthreads();
    }

    // Epilogue: C/D layout col = lane&15, row = quad*4 + r (m89-verified).
#pragma unroll
    for (int i = 0; i < 4; ++i) {
#pragma unroll
        for (int r = 0; r < 4; ++r) {
            const int row = rowA0 + waveM + i * 16 + quad * 4 + r;
            float* cp = C + (size_t)row * N + rowB0 + waveN + l16;
#pragma unroll
            for (int j = 0; j < 4; ++j)
                cp[j * 16] = acc[i][j][r];
        }
    }
}

extern "C" void kernel_launch(void* const* d_in, const int* in_sizes, int n_in,
                              void* d_out, int out_size, void* d_ws, size_t ws_size,
                              hipStream_t stream) {
    const float* x    = (const float*)d_in[0];   // [M, CIN] fp32
    const float* vals = (const float*)d_in[1];   // [nnz] fp32
    const int*   idx  = (const int*)d_in[2];     // [2, nnz] int32

    float* out = (float*)d_out;                  // [M, COUT] fp32

    const int nnz = in_sizes[2] / 2;
    const int M   = in_sizes[0] / CIN;

    const size_t wf_bytes = (size_t)COUT * CIN * sizeof(float);          // 4 MB
    const size_t wb_bytes = (size_t)COUT * CIN * sizeof(unsigned short); // 2 MB

    float*          Wf = (float*)d_ws;
    unsigned short* Wb = (unsigned short*)((char*)d_ws + wf_bytes);
    unsigned short* Xb = (unsigned short*)((char*)d_ws + wf_bytes + wb_bytes);

    // 1) zero fp32 W (ws is poisoned 0xAA before every call)
    zero_f32<<<dim3(COUT * CIN / (256 * 4)), dim3(256), 0, stream>>>((float4*)Wf);
    // 2) scatter-add duplicates like coalesce()
    scatter_add<<<dim3((nnz + 255) / 256), dim3(256), 0, stream>>>(vals, idx, idx + nnz, Wf, nnz);
    // 3) W -> bf16
    cvt_bf16_bulk<<<dim3(COUT * CIN / (256 * 8)), dim3(256), 0, stream>>>(Wf, Wb);
    // 4) x -> bf16 (pure streaming; ws verified large enough in round 3)
    cvt_bf16_bulk<<<dim3((unsigned)((size_t)M * CIN / (256 * 8))), dim3(256), 0, stream>>>(x, Xb);
    // 5) swizzled GEMM: out = x @ W^T
    gemm_bt_bf16_sw<<<dim3(M / 128, COUT / 128), dim3(256), 0, stream>>>(Xb, Wb, out, M);
}